// Round 1
// baseline (206.788 us; speedup 1.0000x reference)
//
#include <hip/hip_runtime.h>
#include <math.h>

// Problem constants
#define PB 2048          // P (sequence length)
#define NB 4             // B (batch)
// ws layout (float offsets), all [b][chan][p] transposed for coalescing
#define OFF_PSI 262144   // comb_t: [4][32][2048] at 0 (rows 0..30 combined, 31 = mask)
#define OFF_ENC 524288   // psi_t (enc_psi, cumsum'd in place)
#define OFF_PRE 786432   // enc_t (phi output)
#define OFF_WV  819200   // pre: [4][4][2048]; wv: [16][33][2048] (w, w*enc), cumsum'd in place

// ---------------------------------------------------------------------------
// K1: per-position encode: combined(31) -> psi MLP -> psi_t ; phi MLP -> enc_t
// One-hot handled sparsely: dense part is rows 0..8 + one looked-up row.
// One-hot row lookup uses stride-33 padded LDS to avoid 64-way bank conflicts.
__global__ __launch_bounds__(128) void k_encode(
    const float* __restrict__ times, const float* __restrict__ vals,
    const int* __restrict__ meas, const float* __restrict__ mask,
    const float* __restrict__ psi_w1, const float* __restrict__ psi_b1,
    const float* __restrict__ psi_w2, const float* __restrict__ psi_b2,
    const float* __restrict__ phi_w1, const float* __restrict__ phi_b1,
    const float* __restrict__ phi_w2, const float* __restrict__ phi_b2,
    float* __restrict__ ws)
{
    // LDS layout:
    // psi_w1 padded 31x33 [0,1023), psi_b1 [1023,1055), psi_w2 [1055,2079), psi_b2 [2079,2111)
    // phi_w1 padded 31x33 [2111,3134), phi_b1 [3134,3166), phi_w2 [3166,4190), phi_b2 [4190,4222)
    __shared__ float sW[4222];
    for (int i = threadIdx.x; i < 1023; i += 128) {
        int r = i / 33, cc = i - r * 33;
        sW[i]        = (cc < 32) ? psi_w1[r*32 + cc] : 0.0f;
        sW[2111 + i] = (cc < 32) ? phi_w1[r*32 + cc] : 0.0f;
    }
    for (int i = threadIdx.x; i < 1024; i += 128) {
        sW[1055 + i] = psi_w2[i];
        sW[3166 + i] = phi_w2[i];
    }
    if (threadIdx.x < 32) {
        int i = threadIdx.x;
        sW[1023 + i] = psi_b1[i];
        sW[2079 + i] = psi_b2[i];
        sW[3134 + i] = phi_b1[i];
        sW[4190 + i] = phi_b2[i];
    }
    __syncthreads();

    const int pp = blockIdx.x * 128 + threadIdx.x;
    const int b = pp >> 11, p = pp & 2047;
    const float t = times[pp];
    const float v = vals[pp];
    const float msk = mask[pp];
    const int m = meas[pp];

    float c[9];
    c[0] = sinf(t);           c[1] = cosf(t);
    c[2] = sinf(t * 0.1f);    c[3] = cosf(t * 0.1f);
    c[4] = sinf(t * 0.01f);   c[5] = cosf(t * 0.01f);
    c[6] = sinf(t * 0.001f);  c[7] = cosf(t * 0.001f);
    c[8] = v;

    float* comb_t = ws;
    float* psi_t  = ws + OFF_PSI;
    float* enc_t  = ws + OFF_ENC;
    const int cb = b * 32;

    // store combined (unmasked, as the reference concatenates raw combined)
    #pragma unroll
    for (int i = 0; i < 8; i++) comb_t[(cb + i) * PB + p] = c[i];
    comb_t[(cb + 8) * PB + p] = v;
    #pragma unroll
    for (int k = 9; k < 31; k++)
        comb_t[(cb + k) * PB + p] = (k == 8 + m) ? 1.0f : 0.0f;
    comb_t[(cb + 31) * PB + p] = msk;

    float x[9];
    #pragma unroll
    for (int i = 0; i < 9; i++) x[i] = c[i] * msk;
    const float ohs = (m > 0) ? msk : 0.0f;          // one-hot * mask
    const int   ohr = (m > 0) ? (8 + m) * 33 : 0;    // padded row offset (safe when m==0)

    // ---- psi MLP ----
    {
        float h1[32];
        #pragma unroll
        for (int j = 0; j < 32; j++) {
            float acc = sW[1023 + j];
            #pragma unroll
            for (int i = 0; i < 9; i++) acc = fmaf(x[i], sW[i*33 + j], acc);
            acc = fmaf(ohs, sW[ohr + j], acc);
            h1[j] = fmaxf(acc, 0.0f) * msk;
        }
        #pragma unroll
        for (int j = 0; j < 32; j++) {
            float acc = sW[2079 + j];
            #pragma unroll
            for (int i = 0; i < 32; i++) acc = fmaf(h1[i], sW[1055 + i*32 + j], acc);
            psi_t[(cb + j) * PB + p] = fmaxf(acc, 0.0f) * msk;
        }
    }
    // ---- phi MLP ----
    {
        float h1[32];
        #pragma unroll
        for (int j = 0; j < 32; j++) {
            float acc = sW[3134 + j];
            #pragma unroll
            for (int i = 0; i < 9; i++) acc = fmaf(x[i], sW[2111 + i*33 + j], acc);
            acc = fmaf(ohs, sW[2111 + ohr + j], acc);
            h1[j] = fmaxf(acc, 0.0f) * msk;
        }
        #pragma unroll
        for (int j = 0; j < 32; j++) {
            float acc = sW[4190 + j];
            #pragma unroll
            for (int i = 0; i < 32; i++) acc = fmaf(h1[i], sW[3166 + i*32 + j], acc);
            enc_t[(cb + j) * PB + p] = fmaxf(acc, 0.0f) * msk;
        }
    }
}

// ---------------------------------------------------------------------------
// K2/K4c: in-place inclusive cumsum of one contiguous 2048-float channel per
// block (one wave). Lane owns 32 contiguous elems; wave-scan of lane totals.
__global__ __launch_bounds__(64) void k_scan(float* __restrict__ data)
{
    float* base = data + (size_t)blockIdx.x * PB;
    const int lane = threadIdx.x;
    float v[32];
    float4* b4 = (float4*)(base + lane * 32);
    #pragma unroll
    for (int k = 0; k < 8; k++) {
        float4 f = b4[k];
        v[4*k] = f.x; v[4*k+1] = f.y; v[4*k+2] = f.z; v[4*k+3] = f.w;
    }
    #pragma unroll
    for (int j = 1; j < 32; j++) v[j] += v[j-1];
    const float tot = v[31];
    float x = tot;
    #pragma unroll
    for (int off = 1; off < 64; off <<= 1) {
        float y = __shfl_up(x, off);
        if (lane >= off) x += y;
    }
    const float excl = x - tot;
    #pragma unroll
    for (int j = 0; j < 32; j++) v[j] += excl;
    #pragma unroll
    for (int k = 0; k < 8; k++)
        b4[k] = make_float4(v[4*k], v[4*k+1], v[4*k+2], v[4*k+3]);
}

// ---------------------------------------------------------------------------
// K3: agg = (cumsum/count)@arho + b ; comb2 = [combined, agg] ;
// preattn[h] = comb2 . U[:,h] where U = fold(W_k, W_q)/sqrt(DOT)  (63x4)
__global__ __launch_bounds__(128) void k_attnpre(
    const float* __restrict__ arho_w, const float* __restrict__ arho_b,
    const float* __restrict__ W_k, const float* __restrict__ W_q,
    float* __restrict__ ws)
{
    __shared__ float sA[1024];
    __shared__ float sAb[32];
    __shared__ float sU[252];
    for (int i = threadIdx.x; i < 1024; i += 128) sA[i] = arho_w[i];
    if (threadIdx.x < 32) sAb[threadIdx.x] = arho_b[threadIdx.x];
    for (int t = threadIdx.x; t < 252; t += 128) {
        int i = t >> 2, h = t & 3;
        float s = 0.0f;
        #pragma unroll
        for (int d = 0; d < 16; d++)
            s = fmaf(W_k[i*64 + d*4 + h], W_q[h*16 + d], s);
        sU[t] = s * 0.25f;   // 1/sqrt(16)
    }
    __syncthreads();

    const int pp = blockIdx.x * 128 + threadIdx.x;
    const int b = pp >> 11, p = pp & 2047;
    const float* comb_t = ws;
    const float* psi_t  = ws + OFF_PSI;
    float* pre = ws + OFF_PRE;
    const int cb = b * 32;
    const float msk = comb_t[(cb + 31) * PB + p];
    const float inv = 1.0f / (float)(p + 1);

    float ag[32];
    #pragma unroll
    for (int ch = 0; ch < 32; ch++)
        ag[ch] = psi_t[(cb + ch) * PB + p] * inv * msk;

    float c2[63];
    #pragma unroll
    for (int i = 0; i < 31; i++) c2[i] = comb_t[(cb + i) * PB + p];
    #pragma unroll
    for (int j = 0; j < 32; j++) {
        float acc = sAb[j];
        #pragma unroll
        for (int ch = 0; ch < 32; ch++) acc = fmaf(ag[ch], sA[ch*32 + j], acc);
        c2[31 + j] = acc * msk;
    }

    float pr0 = 0.f, pr1 = 0.f, pr2 = 0.f, pr3 = 0.f;
    #pragma unroll
    for (int i = 0; i < 63; i++) {
        const float ci = c2[i];
        pr0 = fmaf(ci, sU[i*4 + 0], pr0);
        pr1 = fmaf(ci, sU[i*4 + 1], pr1);
        pr2 = fmaf(ci, sU[i*4 + 2], pr2);
        pr3 = fmaf(ci, sU[i*4 + 3], pr3);
    }
    pre[(b*4 + 0) * PB + p] = pr0 * msk;
    pre[(b*4 + 1) * PB + p] = pr1 * msk;
    pre[(b*4 + 2) * PB + p] = pr2 * msk;
    pre[(b*4 + 3) * PB + p] = pr3 * msk;
}

// ---------------------------------------------------------------------------
// K4: per (b,h): M = max_p s ; w = exp(s-M) ; emit w and w*enc (33 channels).
// Global max instead of cummax: ratios C/L are mathematically identical.
__global__ __launch_bounds__(256) void k_weights(float* __restrict__ ws)
{
    const int bh = blockIdx.x;
    const int b = bh >> 2;
    const float* s = ws + OFF_PRE + (size_t)bh * PB;
    const float* enc_t = ws + OFF_ENC + (size_t)b * 32 * PB;
    float* wv = ws + OFF_WV + (size_t)bh * 33 * PB;

    __shared__ float red[256];
    const int tid = threadIdx.x;
    float mx = -1e30f;
    #pragma unroll
    for (int r = 0; r < 8; r++) mx = fmaxf(mx, s[tid + 256*r]);
    red[tid] = mx;
    __syncthreads();
    for (int st = 128; st > 0; st >>= 1) {
        if (tid < st) red[tid] = fmaxf(red[tid], red[tid + st]);
        __syncthreads();
    }
    const float M = red[0];

    #pragma unroll
    for (int r = 0; r < 8; r++) {
        const int p = tid + 256 * r;
        const float w = expf(s[p] - M);
        wv[p] = w;
        #pragma unroll
        for (int d = 0; d < 32; d++)
            wv[(size_t)(1 + d) * PB + p] = w * enc_t[(size_t)d * PB + p];
    }
}

// ---------------------------------------------------------------------------
// K5: out5 = C/L -> agg2(128) -> rho MLP (128->64->64).
// 64 positions per block; 4 waves split the 64 outputs (16 each); weights are
// wave-uniform (readfirstlane -> scalar loads); h1 exchanged via LDS.
__global__ __launch_bounds__(256, 1) void k_rho(
    const float* __restrict__ rho_w1, const float* __restrict__ rho_b1,
    const float* __restrict__ rho_w2, const float* __restrict__ rho_b2,
    const float* __restrict__ ws, float* __restrict__ out)
{
    __shared__ float h1buf[64 * 64];   // [j][pos]
    __shared__ float obuf[64 * 65];    // [pos][j], padded
    const int tid = threadIdx.x;
    const int lane = tid & 63;                 // position within group
    const int j0 = (tid >> 6) << 4;            // this wave's output base
    const int j0s = __builtin_amdgcn_readfirstlane(j0);
    const int pbase = blockIdx.x * 64;
    const int b = pbase >> 11;
    const int pl = (pbase & 2047) + lane;
    const float* wv = ws + OFF_WV + (size_t)b * 4 * 33 * PB;
    const float msk = ws[(b*32 + 31) * PB + pl];

    float a2[128];
    #pragma unroll
    for (int h = 0; h < 4; h++) {
        const float invL = 1.0f / wv[(size_t)(h*33) * PB + pl];
        #pragma unroll
        for (int d = 0; d < 32; d++)
            a2[h*32 + d] = wv[(size_t)(h*33 + 1 + d) * PB + pl] * invL * msk;
    }

    float acc[16];
    #pragma unroll
    for (int k = 0; k < 16; k++) acc[k] = rho_b1[j0s + k];
    #pragma unroll
    for (int i = 0; i < 128; i++) {
        const float* wrow = rho_w1 + i*64 + j0s;   // wave-uniform -> s_load
        const float ai = a2[i];
        #pragma unroll
        for (int k = 0; k < 16; k++) acc[k] = fmaf(ai, wrow[k], acc[k]);
    }
    #pragma unroll
    for (int k = 0; k < 16; k++)
        h1buf[(j0 + k) * 64 + lane] = fmaxf(acc[k], 0.0f) * msk;
    __syncthreads();

    float acc2[16];
    #pragma unroll
    for (int k = 0; k < 16; k++) acc2[k] = rho_b2[j0s + k];
    #pragma unroll
    for (int i = 0; i < 64; i++) {
        const float hv = h1buf[i * 64 + lane];
        const float* wrow = rho_w2 + i*64 + j0s;
        #pragma unroll
        for (int k = 0; k < 16; k++) acc2[k] = fmaf(hv, wrow[k], acc2[k]);
    }
    #pragma unroll
    for (int k = 0; k < 16; k++)
        obuf[lane * 65 + j0 + k] = fmaxf(acc2[k], 0.0f) * msk;
    __syncthreads();

    for (int idx = tid; idx < 4096; idx += 256) {
        const int pos = idx >> 6, j = idx & 63;
        out[(size_t)(pbase + pos) * 64 + j] = obuf[pos * 65 + j];
    }
}

// ---------------------------------------------------------------------------
extern "C" void kernel_launch(void* const* d_in, const int* in_sizes, int n_in,
                              void* d_out, int out_size, void* d_ws, size_t ws_size,
                              hipStream_t stream)
{
    const float* times  = (const float*)d_in[0];
    const float* vals   = (const float*)d_in[1];
    const int*   meas   = (const int*)d_in[2];
    const float* mask   = (const float*)d_in[3];
    const float* psi_w1 = (const float*)d_in[4];
    const float* psi_b1 = (const float*)d_in[5];
    const float* psi_w2 = (const float*)d_in[6];
    const float* psi_b2 = (const float*)d_in[7];
    const float* arho_w = (const float*)d_in[8];
    const float* arho_b = (const float*)d_in[9];
    const float* W_k    = (const float*)d_in[10];
    const float* W_q    = (const float*)d_in[11];
    const float* phi_w1 = (const float*)d_in[12];
    const float* phi_b1 = (const float*)d_in[13];
    const float* phi_w2 = (const float*)d_in[14];
    const float* phi_b2 = (const float*)d_in[15];
    const float* rho_w1 = (const float*)d_in[16];
    const float* rho_b1 = (const float*)d_in[17];
    const float* rho_w2 = (const float*)d_in[18];
    const float* rho_b2 = (const float*)d_in[19];
    float* ws  = (float*)d_ws;
    float* out = (float*)d_out;

    k_encode<<<dim3(64), dim3(128), 0, stream>>>(times, vals, meas, mask,
        psi_w1, psi_b1, psi_w2, psi_b2, phi_w1, phi_b1, phi_w2, phi_b2, ws);
    k_scan<<<dim3(128), dim3(64), 0, stream>>>(ws + OFF_PSI);               // cumsum enc_psi
    k_attnpre<<<dim3(64), dim3(128), 0, stream>>>(arho_w, arho_b, W_k, W_q, ws);
    k_weights<<<dim3(16), dim3(256), 0, stream>>>(ws);
    k_scan<<<dim3(528), dim3(64), 0, stream>>>(ws + OFF_WV);                // cumsum w, w*enc
    k_rho<<<dim3(128), dim3(256), 0, stream>>>(rho_w1, rho_b1, rho_w2, rho_b2, ws, out);
}

// Round 2
// 176.500 us; speedup vs baseline: 1.1716x; 1.1716x over previous
//
#include <hip/hip_runtime.h>
#include <math.h>

// Problem constants
#define PB 2048          // P (sequence length)
// ws layout (float offsets), all [b][chan][p] transposed for coalescing
#define OFF_PSI 262144   // comb_t: [4][32][2048] at 0 (rows 0..30 combined, 31 = mask)
#define OFF_ENC 524288   // psi_t (enc_psi, cumsum'd in place)
#define OFF_PRE 786432   // enc_t (phi output)
#define OFF_WV  819200   // pre: [4][4][2048]
#define OFF_M   1900544  // wv: [16][33][2048]; then M_enc: 16 uint32

// ordered-uint encoding for float atomicMax (monotone for all finite floats)
__device__ __forceinline__ unsigned f2o(float f) {
    unsigned u = __float_as_uint(f);
    return (u & 0x80000000u) ? ~u : (u | 0x80000000u);
}
__device__ __forceinline__ float o2f(unsigned u) {
    return (u & 0x80000000u) ? __uint_as_float(u & 0x7fffffffu)
                             : __uint_as_float(~u);
}

// ---------------------------------------------------------------------------
// K1: per-position encode: combined(31) -> psi MLP -> psi_t ; phi MLP -> enc_t
// One-hot handled sparsely; padded stride-33 LDS rows avoid same-bank lookup.
// Also initializes the 16-entry M_enc atomic-max buffer (block 0).
__global__ __launch_bounds__(64) void k_encode(
    const float* __restrict__ times, const float* __restrict__ vals,
    const int* __restrict__ meas, const float* __restrict__ mask,
    const float* __restrict__ psi_w1, const float* __restrict__ psi_b1,
    const float* __restrict__ psi_w2, const float* __restrict__ psi_b2,
    const float* __restrict__ phi_w1, const float* __restrict__ phi_b1,
    const float* __restrict__ phi_w2, const float* __restrict__ phi_b2,
    float* __restrict__ ws)
{
    // psi_w1 31x33 [0,1023), psi_b1 [1023,1055), psi_w2 [1055,2079), psi_b2 [2079,2111)
    // phi_w1 31x33 [2111,3134), phi_b1 [3134,3166), phi_w2 [3166,4190), phi_b2 [4190,4222)
    __shared__ float sW[4222];
    for (int i = threadIdx.x; i < 1023; i += 64) {
        int r = i / 33, cc = i - r * 33;
        sW[i]        = (cc < 32) ? psi_w1[r*32 + cc] : 0.0f;
        sW[2111 + i] = (cc < 32) ? phi_w1[r*32 + cc] : 0.0f;
    }
    for (int i = threadIdx.x; i < 1024; i += 64) {
        sW[1055 + i] = psi_w2[i];
        sW[3166 + i] = phi_w2[i];
    }
    if (threadIdx.x < 32) {
        int i = threadIdx.x;
        sW[1023 + i] = psi_b1[i];
        sW[2079 + i] = psi_b2[i];
        sW[3134 + i] = phi_b1[i];
        sW[4190 + i] = phi_b2[i];
    }
    if (blockIdx.x == 0 && threadIdx.x < 16)
        ((unsigned*)(ws + OFF_M))[threadIdx.x] = 0u;  // below all finite encodings
    __syncthreads();

    const int pp = blockIdx.x * 64 + threadIdx.x;
    const int b = pp >> 11, p = pp & 2047;
    const float t = times[pp];
    const float v = vals[pp];
    const float msk = mask[pp];
    const int m = meas[pp];

    float c[9];
    c[0] = sinf(t);           c[1] = cosf(t);
    c[2] = sinf(t * 0.1f);    c[3] = cosf(t * 0.1f);
    c[4] = sinf(t * 0.01f);   c[5] = cosf(t * 0.01f);
    c[6] = sinf(t * 0.001f);  c[7] = cosf(t * 0.001f);
    c[8] = v;

    float* comb_t = ws;
    float* psi_t  = ws + OFF_PSI;
    float* enc_t  = ws + OFF_ENC;
    const int cb = b * 32;

    #pragma unroll
    for (int i = 0; i < 8; i++) comb_t[(cb + i) * PB + p] = c[i];
    comb_t[(cb + 8) * PB + p] = v;
    #pragma unroll
    for (int k = 9; k < 31; k++)
        comb_t[(cb + k) * PB + p] = (k == 8 + m) ? 1.0f : 0.0f;
    comb_t[(cb + 31) * PB + p] = msk;

    float x[9];
    #pragma unroll
    for (int i = 0; i < 9; i++) x[i] = c[i] * msk;
    const float ohs = (m > 0) ? msk : 0.0f;
    const int   ohr = (m > 0) ? (8 + m) * 33 : 0;

    // ---- psi MLP ----
    {
        float h1[32];
        #pragma unroll
        for (int j = 0; j < 32; j++) {
            float acc = sW[1023 + j];
            #pragma unroll
            for (int i = 0; i < 9; i++) acc = fmaf(x[i], sW[i*33 + j], acc);
            acc = fmaf(ohs, sW[ohr + j], acc);
            h1[j] = fmaxf(acc, 0.0f) * msk;
        }
        #pragma unroll
        for (int j = 0; j < 32; j++) {
            float acc = sW[2079 + j];
            #pragma unroll
            for (int i = 0; i < 32; i++) acc = fmaf(h1[i], sW[1055 + i*32 + j], acc);
            psi_t[(cb + j) * PB + p] = fmaxf(acc, 0.0f) * msk;
        }
    }
    // ---- phi MLP ----
    {
        float h1[32];
        #pragma unroll
        for (int j = 0; j < 32; j++) {
            float acc = sW[3134 + j];
            #pragma unroll
            for (int i = 0; i < 9; i++) acc = fmaf(x[i], sW[2111 + i*33 + j], acc);
            acc = fmaf(ohs, sW[2111 + ohr + j], acc);
            h1[j] = fmaxf(acc, 0.0f) * msk;
        }
        #pragma unroll
        for (int j = 0; j < 32; j++) {
            float acc = sW[4190 + j];
            #pragma unroll
            for (int i = 0; i < 32; i++) acc = fmaf(h1[i], sW[3166 + i*32 + j], acc);
            enc_t[(cb + j) * PB + p] = fmaxf(acc, 0.0f) * msk;
        }
    }
}

// ---------------------------------------------------------------------------
// K2: in-place inclusive cumsum of one 2048-float channel per block (1 wave).
__global__ __launch_bounds__(64) void k_scan(float* __restrict__ data)
{
    float* base = data + (size_t)blockIdx.x * PB;
    const int lane = threadIdx.x;
    float v[32];
    float4* b4 = (float4*)(base + lane * 32);
    #pragma unroll
    for (int k = 0; k < 8; k++) {
        float4 f = b4[k];
        v[4*k] = f.x; v[4*k+1] = f.y; v[4*k+2] = f.z; v[4*k+3] = f.w;
    }
    #pragma unroll
    for (int j = 1; j < 32; j++) v[j] += v[j-1];
    const float tot = v[31];
    float x = tot;
    #pragma unroll
    for (int off = 1; off < 64; off <<= 1) {
        float y = __shfl_up(x, off);
        if (lane >= off) x += y;
    }
    const float excl = x - tot;
    #pragma unroll
    for (int j = 0; j < 32; j++) v[j] += excl;
    #pragma unroll
    for (int k = 0; k < 8; k++)
        b4[k] = make_float4(v[4*k], v[4*k+1], v[4*k+2], v[4*k+3]);
}

// ---------------------------------------------------------------------------
// K3: agg = (cumsum/count)@arho + b ; preattn[h] = [combined,agg] . U[:,h]
// with U = fold(W_k,W_q)/sqrt(DOT); also wave-max -> atomicMax into M_enc.
__global__ __launch_bounds__(64) void k_attnpre(
    const float* __restrict__ arho_w, const float* __restrict__ arho_b,
    const float* __restrict__ W_k, const float* __restrict__ W_q,
    float* __restrict__ ws)
{
    __shared__ float sA[1024];
    __shared__ float sAb[32];
    __shared__ float sU[252];
    for (int i = threadIdx.x; i < 1024; i += 64) sA[i] = arho_w[i];
    if (threadIdx.x < 32) sAb[threadIdx.x] = arho_b[threadIdx.x];
    for (int t = threadIdx.x; t < 252; t += 64) {
        int i = t >> 2, h = t & 3;
        float s = 0.0f;
        #pragma unroll
        for (int d = 0; d < 16; d++)
            s = fmaf(W_k[i*64 + d*4 + h], W_q[h*16 + d], s);
        sU[t] = s * 0.25f;   // 1/sqrt(16)
    }
    __syncthreads();

    const int pp = blockIdx.x * 64 + threadIdx.x;
    const int b = pp >> 11, p = pp & 2047;
    const float* comb_t = ws;
    const float* psi_t  = ws + OFF_PSI;
    float* pre = ws + OFF_PRE;
    const int cb = b * 32;
    const float msk = comb_t[(cb + 31) * PB + p];
    const float inv = 1.0f / (float)(p + 1);

    float ag[32];
    #pragma unroll
    for (int ch = 0; ch < 32; ch++)
        ag[ch] = psi_t[(cb + ch) * PB + p] * inv * msk;

    float c2[63];
    #pragma unroll
    for (int i = 0; i < 31; i++) c2[i] = comb_t[(cb + i) * PB + p];
    #pragma unroll
    for (int j = 0; j < 32; j++) {
        float acc = sAb[j];
        #pragma unroll
        for (int ch = 0; ch < 32; ch++) acc = fmaf(ag[ch], sA[ch*32 + j], acc);
        c2[31 + j] = acc * msk;
    }

    float pr[4] = {0.f, 0.f, 0.f, 0.f};
    #pragma unroll
    for (int i = 0; i < 63; i++) {
        const float ci = c2[i];
        #pragma unroll
        for (int h = 0; h < 4; h++) pr[h] = fmaf(ci, sU[i*4 + h], pr[h]);
    }
    #pragma unroll
    for (int h = 0; h < 4; h++) pr[h] *= msk;

    #pragma unroll
    for (int h = 0; h < 4; h++)
        pre[(b*4 + h) * PB + p] = pr[h];

    // wave-level max per head, then one atomic per wave per head
    float mx[4] = {pr[0], pr[1], pr[2], pr[3]};
    #pragma unroll
    for (int off = 32; off > 0; off >>= 1) {
        #pragma unroll
        for (int h = 0; h < 4; h++)
            mx[h] = fmaxf(mx[h], __shfl_xor(mx[h], off));
    }
    if (threadIdx.x == 0) {
        unsigned* M = (unsigned*)(ws + OFF_M);
        #pragma unroll
        for (int h = 0; h < 4; h++)
            atomicMax(&M[b*4 + h], f2o(mx[h]));
    }
}

// ---------------------------------------------------------------------------
// K4: fused weights+scan. Block = one (bh, c) channel, c in [0,33):
//   c==0 : v = exp(s - M)            (denominator L)
//   c>0  : v = exp(s - M) * enc[c-1] (numerator C)
// then in-place style inclusive cumsum written to wv channel.
__global__ __launch_bounds__(64) void k_scan2w(float* __restrict__ ws)
{
    const int blk = blockIdx.x;
    const int bh = blk / 33;
    const int c  = blk - bh * 33;
    const int b  = bh >> 2;
    const int lane = threadIdx.x;

    const float M = o2f(((const unsigned*)(ws + OFF_M))[bh]);
    const float4* s4 = (const float4*)(ws + OFF_PRE + (size_t)bh * PB + lane * 32);
    const float4* e4 = (const float4*)(ws + OFF_ENC + ((size_t)(b*32 + (c-1))) * PB + lane * 32);
    float4* o4 = (float4*)(ws + OFF_WV + ((size_t)(bh*33 + c)) * PB + lane * 32);

    float v[32];
    #pragma unroll
    for (int k = 0; k < 8; k++) {
        float4 f = s4[k];
        v[4*k] = f.x; v[4*k+1] = f.y; v[4*k+2] = f.z; v[4*k+3] = f.w;
    }
    #pragma unroll
    for (int j = 0; j < 32; j++) v[j] = expf(v[j] - M);
    if (c > 0) {
        #pragma unroll
        for (int k = 0; k < 8; k++) {
            float4 f = e4[k];
            v[4*k] *= f.x; v[4*k+1] *= f.y; v[4*k+2] *= f.z; v[4*k+3] *= f.w;
        }
    }
    #pragma unroll
    for (int j = 1; j < 32; j++) v[j] += v[j-1];
    const float tot = v[31];
    float x = tot;
    #pragma unroll
    for (int off = 1; off < 64; off <<= 1) {
        float y = __shfl_up(x, off);
        if (lane >= off) x += y;
    }
    const float excl = x - tot;
    #pragma unroll
    for (int j = 0; j < 32; j++) v[j] += excl;
    #pragma unroll
    for (int k = 0; k < 8; k++)
        o4[k] = make_float4(v[4*k], v[4*k+1], v[4*k+2], v[4*k+3]);
}

// ---------------------------------------------------------------------------
// K5: out5 = C/L -> agg2(128) -> rho MLP (128->64->64).
// 64 positions/block; 4 waves x 16 outputs; a2 STREAMED (no per-thread array
// -> no scratch spill); weights via wave-uniform scalar loads.
__global__ __launch_bounds__(256) void k_rho(
    const float* __restrict__ rho_w1, const float* __restrict__ rho_b1,
    const float* __restrict__ rho_w2, const float* __restrict__ rho_b2,
    const float* __restrict__ ws, float* __restrict__ out)
{
    __shared__ float h1buf[64 * 64];   // [j][pos]
    __shared__ float obuf[64 * 65];    // [pos][j], padded
    const int tid = threadIdx.x;
    const int lane = tid & 63;
    const int j0 = (tid >> 6) << 4;
    const int j0s = __builtin_amdgcn_readfirstlane(j0);
    const int pbase = blockIdx.x * 64;
    const int b = pbase >> 11;
    const int pl = (pbase & 2047) + lane;
    const float* wv = ws + OFF_WV + (size_t)b * 4 * 33 * PB;
    const float msk = ws[(b*32 + 31) * PB + pl];

    float scale[4];
    #pragma unroll
    for (int h = 0; h < 4; h++)
        scale[h] = msk / wv[(size_t)(h*33) * PB + pl];

    float acc[16];
    #pragma unroll
    for (int k = 0; k < 16; k++) acc[k] = rho_b1[j0s + k];
    #pragma unroll
    for (int h = 0; h < 4; h++) {
        #pragma unroll
        for (int d = 0; d < 32; d++) {
            const float ai = wv[(size_t)(h*33 + 1 + d) * PB + pl] * scale[h];
            const float* wrow = rho_w1 + (h*32 + d)*64 + j0s;  // wave-uniform
            #pragma unroll
            for (int k = 0; k < 16; k++) acc[k] = fmaf(ai, wrow[k], acc[k]);
        }
    }
    #pragma unroll
    for (int k = 0; k < 16; k++)
        h1buf[(j0 + k) * 64 + lane] = fmaxf(acc[k], 0.0f) * msk;
    __syncthreads();

    float acc2[16];
    #pragma unroll
    for (int k = 0; k < 16; k++) acc2[k] = rho_b2[j0s + k];
    #pragma unroll
    for (int i = 0; i < 64; i++) {
        const float hv = h1buf[i * 64 + lane];
        const float* wrow = rho_w2 + i*64 + j0s;
        #pragma unroll
        for (int k = 0; k < 16; k++) acc2[k] = fmaf(hv, wrow[k], acc2[k]);
    }
    #pragma unroll
    for (int k = 0; k < 16; k++)
        obuf[lane * 65 + j0 + k] = fmaxf(acc2[k], 0.0f) * msk;
    __syncthreads();

    for (int idx = tid; idx < 4096; idx += 256) {
        const int pos = idx >> 6, j = idx & 63;
        out[(size_t)(pbase + pos) * 64 + j] = obuf[pos * 65 + j];
    }
}

// ---------------------------------------------------------------------------
extern "C" void kernel_launch(void* const* d_in, const int* in_sizes, int n_in,
                              void* d_out, int out_size, void* d_ws, size_t ws_size,
                              hipStream_t stream)
{
    const float* times  = (const float*)d_in[0];
    const float* vals   = (const float*)d_in[1];
    const int*   meas   = (const int*)d_in[2];
    const float* mask   = (const float*)d_in[3];
    const float* psi_w1 = (const float*)d_in[4];
    const float* psi_b1 = (const float*)d_in[5];
    const float* psi_w2 = (const float*)d_in[6];
    const float* psi_b2 = (const float*)d_in[7];
    const float* arho_w = (const float*)d_in[8];
    const float* arho_b = (const float*)d_in[9];
    const float* W_k    = (const float*)d_in[10];
    const float* W_q    = (const float*)d_in[11];
    const float* phi_w1 = (const float*)d_in[12];
    const float* phi_b1 = (const float*)d_in[13];
    const float* phi_w2 = (const float*)d_in[14];
    const float* phi_b2 = (const float*)d_in[15];
    const float* rho_w1 = (const float*)d_in[16];
    const float* rho_b1 = (const float*)d_in[17];
    const float* rho_w2 = (const float*)d_in[18];
    const float* rho_b2 = (const float*)d_in[19];
    float* ws  = (float*)d_ws;
    float* out = (float*)d_out;

    k_encode<<<dim3(128), dim3(64), 0, stream>>>(times, vals, meas, mask,
        psi_w1, psi_b1, psi_w2, psi_b2, phi_w1, phi_b1, phi_w2, phi_b2, ws);
    k_scan<<<dim3(128), dim3(64), 0, stream>>>(ws + OFF_PSI);      // cumsum enc_psi
    k_attnpre<<<dim3(128), dim3(64), 0, stream>>>(arho_w, arho_b, W_k, W_q, ws);
    k_scan2w<<<dim3(528), dim3(64), 0, stream>>>(ws);              // exp+scan fused
    k_rho<<<dim3(128), dim3(256), 0, stream>>>(rho_w1, rho_b1, rho_w2, rho_b2, ws, out);
}

// Round 3
// 146.442 us; speedup vs baseline: 1.4121x; 1.2053x over previous
//
#include <hip/hip_runtime.h>
#include <math.h>

// Problem constants
#define PB 2048          // P (sequence length)
// ws layout (float offsets), all [b][chan][p] transposed for coalescing
#define OFF_PSI 262144   // comb_t: [4][32][2048] at 0 (rows 0..30 combined, 31 = mask)
#define OFF_ENC 524288   // psi_t (enc_psi, cumsum'd in place)
#define OFF_PRE 786432   // enc_t (phi output)
#define OFF_WV  819200   // pre: [4][4][2048] holds exp(s)
                         // wv: [16][33][2048] (w, w*enc), scanned

// ---------------------------------------------------------------------------
// K1: per-position encode: combined(31) -> psi MLP -> psi_t ; phi MLP -> enc_t
__global__ __launch_bounds__(64) void k_encode(
    const float* __restrict__ times, const float* __restrict__ vals,
    const int* __restrict__ meas, const float* __restrict__ mask,
    const float* __restrict__ psi_w1, const float* __restrict__ psi_b1,
    const float* __restrict__ psi_w2, const float* __restrict__ psi_b2,
    const float* __restrict__ phi_w1, const float* __restrict__ phi_b1,
    const float* __restrict__ phi_w2, const float* __restrict__ phi_b2,
    float* __restrict__ ws)
{
    // psi_w1 31x33 [0,1023), psi_b1 [1023,1055), psi_w2 [1055,2079), psi_b2 [2079,2111)
    // phi_w1 31x33 [2111,3134), phi_b1 [3134,3166), phi_w2 [3166,4190), phi_b2 [4190,4222)
    __shared__ float sW[4222];
    for (int i = threadIdx.x; i < 1023; i += 64) {
        int r = i / 33, cc = i - r * 33;
        sW[i]        = (cc < 32) ? psi_w1[r*32 + cc] : 0.0f;
        sW[2111 + i] = (cc < 32) ? phi_w1[r*32 + cc] : 0.0f;
    }
    for (int i = threadIdx.x; i < 1024; i += 64) {
        sW[1055 + i] = psi_w2[i];
        sW[3166 + i] = phi_w2[i];
    }
    if (threadIdx.x < 32) {
        int i = threadIdx.x;
        sW[1023 + i] = psi_b1[i];
        sW[2079 + i] = psi_b2[i];
        sW[3134 + i] = phi_b1[i];
        sW[4190 + i] = phi_b2[i];
    }
    __syncthreads();

    const int pp = blockIdx.x * 64 + threadIdx.x;
    const int b = pp >> 11, p = pp & 2047;
    const float t = times[pp];
    const float v = vals[pp];
    const float msk = mask[pp];
    const int m = meas[pp];

    float c[9];
    c[0] = sinf(t);           c[1] = cosf(t);
    c[2] = sinf(t * 0.1f);    c[3] = cosf(t * 0.1f);
    c[4] = sinf(t * 0.01f);   c[5] = cosf(t * 0.01f);
    c[6] = sinf(t * 0.001f);  c[7] = cosf(t * 0.001f);
    c[8] = v;

    float* comb_t = ws;
    float* psi_t  = ws + OFF_PSI;
    float* enc_t  = ws + OFF_ENC;
    const int cb = b * 32;

    #pragma unroll
    for (int i = 0; i < 8; i++) comb_t[(cb + i) * PB + p] = c[i];
    comb_t[(cb + 8) * PB + p] = v;
    #pragma unroll
    for (int k = 9; k < 31; k++)
        comb_t[(cb + k) * PB + p] = (k == 8 + m) ? 1.0f : 0.0f;
    comb_t[(cb + 31) * PB + p] = msk;

    float x[9];
    #pragma unroll
    for (int i = 0; i < 9; i++) x[i] = c[i] * msk;
    const float ohs = (m > 0) ? msk : 0.0f;
    const int   ohr = (m > 0) ? (8 + m) * 33 : 0;

    // ---- psi MLP ----
    {
        float h1[32];
        #pragma unroll
        for (int j = 0; j < 32; j++) {
            float acc = sW[1023 + j];
            #pragma unroll
            for (int i = 0; i < 9; i++) acc = fmaf(x[i], sW[i*33 + j], acc);
            acc = fmaf(ohs, sW[ohr + j], acc);
            h1[j] = fmaxf(acc, 0.0f) * msk;
        }
        #pragma unroll
        for (int j = 0; j < 32; j++) {
            float acc = sW[2079 + j];
            #pragma unroll
            for (int i = 0; i < 32; i++) acc = fmaf(h1[i], sW[1055 + i*32 + j], acc);
            psi_t[(cb + j) * PB + p] = fmaxf(acc, 0.0f) * msk;
        }
    }
    // ---- phi MLP ----
    {
        float h1[32];
        #pragma unroll
        for (int j = 0; j < 32; j++) {
            float acc = sW[3134 + j];
            #pragma unroll
            for (int i = 0; i < 9; i++) acc = fmaf(x[i], sW[2111 + i*33 + j], acc);
            acc = fmaf(ohs, sW[2111 + ohr + j], acc);
            h1[j] = fmaxf(acc, 0.0f) * msk;
        }
        #pragma unroll
        for (int j = 0; j < 32; j++) {
            float acc = sW[4190 + j];
            #pragma unroll
            for (int i = 0; i < 32; i++) acc = fmaf(h1[i], sW[3166 + i*32 + j], acc);
            enc_t[(cb + j) * PB + p] = fmaxf(acc, 0.0f) * msk;
        }
    }
}

// ---------------------------------------------------------------------------
// K2: in-place inclusive cumsum of one 2048-float channel per block (1 wave).
__global__ __launch_bounds__(64) void k_scan(float* __restrict__ data)
{
    float* base = data + (size_t)blockIdx.x * PB;
    const int lane = threadIdx.x;
    float v[32];
    float4* b4 = (float4*)(base + lane * 32);
    #pragma unroll
    for (int k = 0; k < 8; k++) {
        float4 f = b4[k];
        v[4*k] = f.x; v[4*k+1] = f.y; v[4*k+2] = f.z; v[4*k+3] = f.w;
    }
    #pragma unroll
    for (int j = 1; j < 32; j++) v[j] += v[j-1];
    const float tot = v[31];
    float x = tot;
    #pragma unroll
    for (int off = 1; off < 64; off <<= 1) {
        float y = __shfl_up(x, off);
        if (lane >= off) x += y;
    }
    const float excl = x - tot;
    #pragma unroll
    for (int j = 0; j < 32; j++) v[j] += excl;
    #pragma unroll
    for (int k = 0; k < 8; k++)
        b4[k] = make_float4(v[4*k], v[4*k+1], v[4*k+2], v[4*k+3]);
}

// ---------------------------------------------------------------------------
// K3: preattn via fully folded weights:
//   U (63x4) = fold(W_k, W_q)/sqrt(DOT)
//   s = comb(31).U[0:31] + (cumpsi*inv*msk).V + c, V = arho_w@U[31:63], c = arho_b@U[31:63]
// Stores ex = exp(s*msk)  (cummax shift dropped: it cancels in C/L and |s| is O(1)).
__global__ __launch_bounds__(64) void k_attnpre(
    const float* __restrict__ arho_w, const float* __restrict__ arho_b,
    const float* __restrict__ W_k, const float* __restrict__ W_q,
    float* __restrict__ ws)
{
    __shared__ float sU[31*4];    // combined-part columns
    __shared__ float sU2[32*4];   // agg-part columns (temp)
    __shared__ float sV[32*4];    // arho_w @ U2
    __shared__ float sC[4];       // arho_b @ U2
    for (int t = threadIdx.x; t < 252; t += 64) {
        int i = t >> 2, h = t & 3;
        float s = 0.0f;
        #pragma unroll
        for (int d = 0; d < 16; d++)
            s = fmaf(W_k[i*64 + d*4 + h], W_q[h*16 + d], s);
        s *= 0.25f;   // 1/sqrt(16)
        if (i < 31) sU[i*4 + h] = s; else sU2[(i-31)*4 + h] = s;
    }
    __syncthreads();
    for (int t = threadIdx.x; t < 128; t += 64) {
        int ch = t >> 2, h = t & 3;
        float s = 0.0f;
        #pragma unroll
        for (int j = 0; j < 32; j++)
            s = fmaf(arho_w[ch*32 + j], sU2[j*4 + h], s);
        sV[t] = s;
    }
    if (threadIdx.x < 4) {
        float s = 0.0f;
        #pragma unroll
        for (int j = 0; j < 32; j++)
            s = fmaf(arho_b[j], sU2[j*4 + threadIdx.x], s);
        sC[threadIdx.x] = s;
    }
    __syncthreads();

    const int pp = blockIdx.x * 64 + threadIdx.x;
    const int b = pp >> 11, p = pp & 2047;
    const float* comb_t = ws;
    const float* psi_t  = ws + OFF_PSI;
    float* pre = ws + OFF_PRE;
    const int cb = b * 32;
    const float msk = comb_t[(size_t)(cb + 31) * PB + p];
    const float inv = msk / (float)(p + 1);

    float pr[4] = {sC[0], sC[1], sC[2], sC[3]};
    #pragma unroll
    for (int i = 0; i < 31; i++) {
        const float ci = comb_t[(size_t)(cb + i) * PB + p];
        #pragma unroll
        for (int h = 0; h < 4; h++) pr[h] = fmaf(ci, sU[i*4 + h], pr[h]);
    }
    #pragma unroll
    for (int ch = 0; ch < 32; ch++) {
        const float ag = psi_t[(size_t)(cb + ch) * PB + p] * inv;
        #pragma unroll
        for (int h = 0; h < 4; h++) pr[h] = fmaf(ag, sV[ch*4 + h], pr[h]);
    }
    #pragma unroll
    for (int h = 0; h < 4; h++)
        pre[(size_t)(b*4 + h) * PB + p] = expf(pr[h] * msk);
}

// ---------------------------------------------------------------------------
// K4: fused weight-mul + scan. Block = one (bh, c) channel, c in [0,33):
//   c==0 : v = ex            (denominator L)
//   c>0  : v = ex * enc[c-1] (numerator C)
__global__ __launch_bounds__(64) void k_scan2w(float* __restrict__ ws)
{
    const int blk = blockIdx.x;
    const int bh = blk / 33;
    const int c  = blk - bh * 33;
    const int b  = bh >> 2;
    const int lane = threadIdx.x;

    const float4* s4 = (const float4*)(ws + OFF_PRE + (size_t)bh * PB + lane * 32);
    const float4* e4 = (const float4*)(ws + OFF_ENC + ((size_t)(b*32 + (c-1))) * PB + lane * 32);
    float4* o4 = (float4*)(ws + OFF_WV + ((size_t)(bh*33 + c)) * PB + lane * 32);

    float v[32];
    #pragma unroll
    for (int k = 0; k < 8; k++) {
        float4 f = s4[k];
        v[4*k] = f.x; v[4*k+1] = f.y; v[4*k+2] = f.z; v[4*k+3] = f.w;
    }
    if (c > 0) {
        #pragma unroll
        for (int k = 0; k < 8; k++) {
            float4 f = e4[k];
            v[4*k] *= f.x; v[4*k+1] *= f.y; v[4*k+2] *= f.z; v[4*k+3] *= f.w;
        }
    }
    #pragma unroll
    for (int j = 1; j < 32; j++) v[j] += v[j-1];
    const float tot = v[31];
    float x = tot;
    #pragma unroll
    for (int off = 1; off < 64; off <<= 1) {
        float y = __shfl_up(x, off);
        if (lane >= off) x += y;
    }
    const float excl = x - tot;
    #pragma unroll
    for (int j = 0; j < 32; j++) v[j] += excl;
    #pragma unroll
    for (int k = 0; k < 8; k++)
        o4[k] = make_float4(v[4*k], v[4*k+1], v[4*k+2], v[4*k+3]);
}

// ---------------------------------------------------------------------------
// K5: out5 = C/L -> agg2(128) -> rho MLP (128->64->64).
// 512 blocks x 256 threads; block = 16 positions; thread = (pos, 4-output
// group). Weights via coalesced float4 global loads (L1-hot, 48 KB total);
// h1 via small padded LDS tile; fully coalesced float4 output stores.
__global__ __launch_bounds__(256) void k_rho(
    const float* __restrict__ rho_w1, const float* __restrict__ rho_b1,
    const float* __restrict__ rho_w2, const float* __restrict__ rho_b2,
    const float* __restrict__ ws, float* __restrict__ out)
{
    __shared__ float h1s[16][65];   // [pos][j], 65 keeps banks spread
    __shared__ float scl[16][4];    // msk/L per (pos,h)
    __shared__ float mskS[16];
    const int tid = threadIdx.x;
    const int pos = tid >> 4;       // 0..15
    const int g   = tid & 15;       // output group of 4
    const int pbase = blockIdx.x * 16;
    const int b  = pbase >> 11;
    const int p0 = pbase & 2047;
    const float* wv = ws + OFF_WV + (size_t)b * 132 * PB;   // 4*33 channels

    if (tid < 64) {
        const int pp = tid >> 2, h = tid & 3;
        const float msk = ws[(size_t)(b*32 + 31) * PB + p0 + pp];
        const float L = wv[(size_t)(h*33) * PB + p0 + pp];
        scl[pp][h] = msk / L;
        if (h == 0) mskS[pp] = msk;
    }
    __syncthreads();

    const int pg = p0 + pos;
    float4 acc = ((const float4*)rho_b1)[g];
    const float4* w14 = (const float4*)rho_w1;
    const float sc0 = scl[pos][0], sc1 = scl[pos][1];
    const float sc2 = scl[pos][2], sc3 = scl[pos][3];
    #pragma unroll
    for (int h = 0; h < 4; h++) {
        const float sc = (h == 0) ? sc0 : (h == 1) ? sc1 : (h == 2) ? sc2 : sc3;
        const float* wvh = wv + (size_t)(h*33 + 1) * PB + pg;
        #pragma unroll 8
        for (int d = 0; d < 32; d++) {
            const float ai = wvh[(size_t)d * PB] * sc;
            const float4 w = w14[(h*32 + d)*16 + g];
            acc.x = fmaf(ai, w.x, acc.x);
            acc.y = fmaf(ai, w.y, acc.y);
            acc.z = fmaf(ai, w.z, acc.z);
            acc.w = fmaf(ai, w.w, acc.w);
        }
    }
    const float msk = mskS[pos];
    h1s[pos][g*4+0] = fmaxf(acc.x, 0.f) * msk;
    h1s[pos][g*4+1] = fmaxf(acc.y, 0.f) * msk;
    h1s[pos][g*4+2] = fmaxf(acc.z, 0.f) * msk;
    h1s[pos][g*4+3] = fmaxf(acc.w, 0.f) * msk;
    __syncthreads();

    float4 acc2 = ((const float4*)rho_b2)[g];
    const float4* w24 = (const float4*)rho_w2;
    #pragma unroll 16
    for (int i = 0; i < 64; i++) {
        const float hv = h1s[pos][i];
        const float4 w = w24[i*16 + g];
        acc2.x = fmaf(hv, w.x, acc2.x);
        acc2.y = fmaf(hv, w.y, acc2.y);
        acc2.z = fmaf(hv, w.z, acc2.z);
        acc2.w = fmaf(hv, w.w, acc2.w);
    }
    float4 o;
    o.x = fmaxf(acc2.x, 0.f) * msk;
    o.y = fmaxf(acc2.y, 0.f) * msk;
    o.z = fmaxf(acc2.z, 0.f) * msk;
    o.w = fmaxf(acc2.w, 0.f) * msk;
    ((float4*)out)[(size_t)(pbase + pos) * 16 + g] = o;   // lane-contiguous
}

// ---------------------------------------------------------------------------
extern "C" void kernel_launch(void* const* d_in, const int* in_sizes, int n_in,
                              void* d_out, int out_size, void* d_ws, size_t ws_size,
                              hipStream_t stream)
{
    const float* times  = (const float*)d_in[0];
    const float* vals   = (const float*)d_in[1];
    const int*   meas   = (const int*)d_in[2];
    const float* mask   = (const float*)d_in[3];
    const float* psi_w1 = (const float*)d_in[4];
    const float* psi_b1 = (const float*)d_in[5];
    const float* psi_w2 = (const float*)d_in[6];
    const float* psi_b2 = (const float*)d_in[7];
    const float* arho_w = (const float*)d_in[8];
    const float* arho_b = (const float*)d_in[9];
    const float* W_k    = (const float*)d_in[10];
    const float* W_q    = (const float*)d_in[11];
    const float* phi_w1 = (const float*)d_in[12];
    const float* phi_b1 = (const float*)d_in[13];
    const float* phi_w2 = (const float*)d_in[14];
    const float* phi_b2 = (const float*)d_in[15];
    const float* rho_w1 = (const float*)d_in[16];
    const float* rho_b1 = (const float*)d_in[17];
    const float* rho_w2 = (const float*)d_in[18];
    const float* rho_b2 = (const float*)d_in[19];
    float* ws  = (float*)d_ws;
    float* out = (float*)d_out;

    k_encode<<<dim3(128), dim3(64), 0, stream>>>(times, vals, meas, mask,
        psi_w1, psi_b1, psi_w2, psi_b2, phi_w1, phi_b1, phi_w2, phi_b2, ws);
    k_scan<<<dim3(128), dim3(64), 0, stream>>>(ws + OFF_PSI);      // cumsum enc_psi
    k_attnpre<<<dim3(128), dim3(64), 0, stream>>>(arho_w, arho_b, W_k, W_q, ws);
    k_scan2w<<<dim3(528), dim3(64), 0, stream>>>(ws);              // mul + scan
    k_rho<<<dim3(512), dim3(256), 0, stream>>>(rho_w1, rho_b1, rho_w2, rho_b2, ws, out);
}

// Round 4
// 139.897 us; speedup vs baseline: 1.4781x; 1.0468x over previous
//
#include <hip/hip_runtime.h>
#include <math.h>

// Problem constants
#define PB 2048          // P (sequence length)
// ws layout (float offsets), all [b][chan][p] transposed for coalescing
#define OFF_ENC 0        // enc_t (phi output): [4][32][2048]
#define OFF_Q   262144   // q = psi@V : [4][4][2048]
#define OFF_R   294912   // r = comb@U + c : [4][4][2048]
#define OFF_MSK 327680   // mask: [4][2048]
#define OFF_WV  335872   // wv: [16][33][2048] (scan of w, w*enc)

// ---------------------------------------------------------------------------
// K1: per-position encode.
//   combined(31) -> phi MLP -> enc_t
//   combined(31) -> psi MLP -> q = psi2 @ V   (V = arho_w @ U2, folded here)
//   r = comb @ U[0:31] + arho_b @ U2          (U = fold(W_k,W_q)/sqrt(DOT))
// Linearity: cumsum(psi)@V == cumsum(psi@V), so only 4 scan channels remain.
__global__ __launch_bounds__(64) void k_encode(
    const float* __restrict__ times, const float* __restrict__ vals,
    const int* __restrict__ meas, const float* __restrict__ mask,
    const float* __restrict__ psi_w1, const float* __restrict__ psi_b1,
    const float* __restrict__ psi_w2, const float* __restrict__ psi_b2,
    const float* __restrict__ phi_w1, const float* __restrict__ phi_b1,
    const float* __restrict__ phi_w2, const float* __restrict__ phi_b2,
    const float* __restrict__ arho_w, const float* __restrict__ arho_b,
    const float* __restrict__ W_k, const float* __restrict__ W_q,
    float* __restrict__ ws)
{
    // psi_w1 31x33 [0,1023), psi_b1 [1023,1055), psi_w2 [1055,2079), psi_b2 [2079,2111)
    // phi_w1 31x33 [2111,3134), phi_b1 [3134,3166), phi_w2 [3166,4190), phi_b2 [4190,4222)
    __shared__ float sW[4222];
    __shared__ float sU[31*4];    // combined-part columns of folded key matrix
    __shared__ float sU2[32*4];   // agg-part columns (temp)
    __shared__ float sV[32*4];    // arho_w @ U2
    __shared__ float sCc[4];      // arho_b @ U2
    for (int i = threadIdx.x; i < 1023; i += 64) {
        int r = i / 33, cc = i - r * 33;
        sW[i]        = (cc < 32) ? psi_w1[r*32 + cc] : 0.0f;
        sW[2111 + i] = (cc < 32) ? phi_w1[r*32 + cc] : 0.0f;
    }
    for (int i = threadIdx.x; i < 1024; i += 64) {
        sW[1055 + i] = psi_w2[i];
        sW[3166 + i] = phi_w2[i];
    }
    if (threadIdx.x < 32) {
        int i = threadIdx.x;
        sW[1023 + i] = psi_b1[i];
        sW[2079 + i] = psi_b2[i];
        sW[3134 + i] = phi_b1[i];
        sW[4190 + i] = phi_b2[i];
    }
    for (int t = threadIdx.x; t < 252; t += 64) {
        int i = t >> 2, h = t & 3;
        float s = 0.0f;
        #pragma unroll
        for (int d = 0; d < 16; d++)
            s = fmaf(W_k[i*64 + d*4 + h], W_q[h*16 + d], s);
        s *= 0.25f;   // 1/sqrt(16)
        if (i < 31) sU[i*4 + h] = s; else sU2[(i-31)*4 + h] = s;
    }
    __syncthreads();
    for (int t = threadIdx.x; t < 128; t += 64) {
        int ch = t >> 2, h = t & 3;
        float s = 0.0f;
        #pragma unroll
        for (int j = 0; j < 32; j++)
            s = fmaf(arho_w[ch*32 + j], sU2[j*4 + h], s);
        sV[t] = s;
    }
    if (threadIdx.x < 4) {
        float s = 0.0f;
        #pragma unroll
        for (int j = 0; j < 32; j++)
            s = fmaf(arho_b[j], sU2[j*4 + threadIdx.x], s);
        sCc[threadIdx.x] = s;
    }
    __syncthreads();

    const int pp = blockIdx.x * 64 + threadIdx.x;
    const int b = pp >> 11, p = pp & 2047;
    const float t = times[pp];
    const float v = vals[pp];
    const float msk = mask[pp];
    const int m = meas[pp];

    float c[9];
    c[0] = sinf(t);           c[1] = cosf(t);
    c[2] = sinf(t * 0.1f);    c[3] = cosf(t * 0.1f);
    c[4] = sinf(t * 0.01f);   c[5] = cosf(t * 0.01f);
    c[6] = sinf(t * 0.001f);  c[7] = cosf(t * 0.001f);
    c[8] = v;

    float* enc_t = ws + OFF_ENC;
    const int cb = b * 32;

    float x[9];
    #pragma unroll
    for (int i = 0; i < 9; i++) x[i] = c[i] * msk;
    const float ohs = (m > 0) ? msk : 0.0f;
    const int   ohr = (m > 0) ? (8 + m) * 33 : 0;

    // ---- r = comb @ U + arho_b@U2 (combined is raw/unmasked, per reference)
    float r[4] = {sCc[0], sCc[1], sCc[2], sCc[3]};
    #pragma unroll
    for (int i = 0; i < 9; i++) {
        #pragma unroll
        for (int h = 0; h < 4; h++) r[h] = fmaf(c[i], sU[i*4 + h], r[h]);
    }
    if (m > 0) {
        #pragma unroll
        for (int h = 0; h < 4; h++) r[h] += sU[(8 + m)*4 + h];
    }
    #pragma unroll
    for (int h = 0; h < 4; h++)
        ws[OFF_R + (size_t)(b*4 + h) * PB + p] = r[h];
    ws[OFF_MSK + (size_t)b * PB + p] = msk;

    // ---- psi MLP -> q ----
    {
        float h1[32];
        #pragma unroll
        for (int j = 0; j < 32; j++) {
            float acc = sW[1023 + j];
            #pragma unroll
            for (int i = 0; i < 9; i++) acc = fmaf(x[i], sW[i*33 + j], acc);
            acc = fmaf(ohs, sW[ohr + j], acc);
            h1[j] = fmaxf(acc, 0.0f) * msk;
        }
        float q[4] = {0.f, 0.f, 0.f, 0.f};
        #pragma unroll
        for (int j = 0; j < 32; j++) {
            float acc = sW[2079 + j];
            #pragma unroll
            for (int i = 0; i < 32; i++) acc = fmaf(h1[i], sW[1055 + i*32 + j], acc);
            const float p2 = fmaxf(acc, 0.0f) * msk;
            #pragma unroll
            for (int h = 0; h < 4; h++) q[h] = fmaf(p2, sV[j*4 + h], q[h]);
        }
        #pragma unroll
        for (int h = 0; h < 4; h++)
            ws[OFF_Q + (size_t)(b*4 + h) * PB + p] = q[h];
    }
    // ---- phi MLP -> enc_t ----
    {
        float h1[32];
        #pragma unroll
        for (int j = 0; j < 32; j++) {
            float acc = sW[3134 + j];
            #pragma unroll
            for (int i = 0; i < 9; i++) acc = fmaf(x[i], sW[2111 + i*33 + j], acc);
            acc = fmaf(ohs, sW[2111 + ohr + j], acc);
            h1[j] = fmaxf(acc, 0.0f) * msk;
        }
        #pragma unroll
        for (int j = 0; j < 32; j++) {
            float acc = sW[4190 + j];
            #pragma unroll
            for (int i = 0; i < 32; i++) acc = fmaf(h1[i], sW[3166 + i*32 + j], acc);
            enc_t[(size_t)(cb + j) * PB + p] = fmaxf(acc, 0.0f) * msk;
        }
    }
}

// ---------------------------------------------------------------------------
// K2: fused scan+exp+weight-mul+scan. Block = one (bh, c), c in [0,33):
//   cumq = inclusive-scan(q[bh])                       (redundant per c: cheap)
//   ex   = exp(msk * (r[bh] + cumq/(p+1)))
//   v    = (c==0) ? ex : ex * enc[b][c-1]
//   wv[bh][c] = inclusive-scan(v)
__global__ __launch_bounds__(64) void k_mid(float* __restrict__ ws)
{
    const int blk = blockIdx.x;
    const int bh = blk / 33;
    const int c  = blk - bh * 33;
    const int b  = bh >> 2;
    const int lane = threadIdx.x;

    const float4* q4 = (const float4*)(ws + OFF_Q   + (size_t)bh * PB + lane * 32);
    const float4* r4 = (const float4*)(ws + OFF_R   + (size_t)bh * PB + lane * 32);
    const float4* m4 = (const float4*)(ws + OFF_MSK + (size_t)b  * PB + lane * 32);
    const float4* e4 = (const float4*)(ws + OFF_ENC + ((size_t)(b*32 + (c-1))) * PB + lane * 32);
    float4* o4 = (float4*)(ws + OFF_WV + ((size_t)(bh*33 + c)) * PB + lane * 32);

    float vq[32];
    #pragma unroll
    for (int k = 0; k < 8; k++) {
        float4 f = q4[k];
        vq[4*k] = f.x; vq[4*k+1] = f.y; vq[4*k+2] = f.z; vq[4*k+3] = f.w;
    }
    // inclusive scan of q
    #pragma unroll
    for (int j = 1; j < 32; j++) vq[j] += vq[j-1];
    {
        const float tot = vq[31];
        float x = tot;
        #pragma unroll
        for (int off = 1; off < 64; off <<= 1) {
            float y = __shfl_up(x, off);
            if (lane >= off) x += y;
        }
        const float excl = x - tot;
        #pragma unroll
        for (int j = 0; j < 32; j++) vq[j] += excl;
    }
    // ex = exp(msk*(r + cumq/(p+1))), then multiply by enc channel
    float v[32];
    #pragma unroll
    for (int k = 0; k < 8; k++) {
        const float4 fr = r4[k];
        const float4 fm = m4[k];
        const int p0 = lane * 32 + 4*k;
        v[4*k+0] = expf(fm.x * (fr.x + vq[4*k+0] / (float)(p0 + 1)));
        v[4*k+1] = expf(fm.y * (fr.y + vq[4*k+1] / (float)(p0 + 2)));
        v[4*k+2] = expf(fm.z * (fr.z + vq[4*k+2] / (float)(p0 + 3)));
        v[4*k+3] = expf(fm.w * (fr.w + vq[4*k+3] / (float)(p0 + 4)));
    }
    if (c > 0) {
        #pragma unroll
        for (int k = 0; k < 8; k++) {
            float4 f = e4[k];
            v[4*k] *= f.x; v[4*k+1] *= f.y; v[4*k+2] *= f.z; v[4*k+3] *= f.w;
        }
    }
    // inclusive scan of v
    #pragma unroll
    for (int j = 1; j < 32; j++) v[j] += v[j-1];
    const float tot = v[31];
    float x = tot;
    #pragma unroll
    for (int off = 1; off < 64; off <<= 1) {
        float y = __shfl_up(x, off);
        if (lane >= off) x += y;
    }
    const float excl = x - tot;
    #pragma unroll
    for (int j = 0; j < 32; j++) v[j] += excl;
    #pragma unroll
    for (int k = 0; k < 8; k++)
        o4[k] = make_float4(v[4*k], v[4*k+1], v[4*k+2], v[4*k+3]);
}

// ---------------------------------------------------------------------------
// K3: out5 = C/L -> agg2(128) -> rho MLP (128->64->64).
// 512 blocks x 256 threads; block = 16 positions; thread = (pos, 4-output
// group). Weights via coalesced float4 global loads (L1-hot, 48 KB total).
__global__ __launch_bounds__(256) void k_rho(
    const float* __restrict__ rho_w1, const float* __restrict__ rho_b1,
    const float* __restrict__ rho_w2, const float* __restrict__ rho_b2,
    const float* __restrict__ ws, float* __restrict__ out)
{
    __shared__ float h1s[16][65];   // [pos][j], 65 keeps banks spread
    __shared__ float scl[16][4];    // msk/L per (pos,h)
    __shared__ float mskS[16];
    const int tid = threadIdx.x;
    const int pos = tid >> 4;       // 0..15
    const int g   = tid & 15;       // output group of 4
    const int pbase = blockIdx.x * 16;
    const int b  = pbase >> 11;
    const int p0 = pbase & 2047;
    const float* wv = ws + OFF_WV + (size_t)b * 132 * PB;   // 4*33 channels

    if (tid < 64) {
        const int pp = tid >> 2, h = tid & 3;
        const float msk = ws[OFF_MSK + (size_t)b * PB + p0 + pp];
        const float L = wv[(size_t)(h*33) * PB + p0 + pp];
        scl[pp][h] = msk / L;
        if (h == 0) mskS[pp] = msk;
    }
    __syncthreads();

    const int pg = p0 + pos;
    float4 acc = ((const float4*)rho_b1)[g];
    const float4* w14 = (const float4*)rho_w1;
    const float sc0 = scl[pos][0], sc1 = scl[pos][1];
    const float sc2 = scl[pos][2], sc3 = scl[pos][3];
    #pragma unroll
    for (int h = 0; h < 4; h++) {
        const float sc = (h == 0) ? sc0 : (h == 1) ? sc1 : (h == 2) ? sc2 : sc3;
        const float* wvh = wv + (size_t)(h*33 + 1) * PB + pg;
        #pragma unroll 8
        for (int d = 0; d < 32; d++) {
            const float ai = wvh[(size_t)d * PB] * sc;
            const float4 w = w14[(h*32 + d)*16 + g];
            acc.x = fmaf(ai, w.x, acc.x);
            acc.y = fmaf(ai, w.y, acc.y);
            acc.z = fmaf(ai, w.z, acc.z);
            acc.w = fmaf(ai, w.w, acc.w);
        }
    }
    const float msk = mskS[pos];
    h1s[pos][g*4+0] = fmaxf(acc.x, 0.f) * msk;
    h1s[pos][g*4+1] = fmaxf(acc.y, 0.f) * msk;
    h1s[pos][g*4+2] = fmaxf(acc.z, 0.f) * msk;
    h1s[pos][g*4+3] = fmaxf(acc.w, 0.f) * msk;
    __syncthreads();

    float4 acc2 = ((const float4*)rho_b2)[g];
    const float4* w24 = (const float4*)rho_w2;
    #pragma unroll 16
    for (int i = 0; i < 64; i++) {
        const float hv = h1s[pos][i];
        const float4 w = w24[i*16 + g];
        acc2.x = fmaf(hv, w.x, acc2.x);
        acc2.y = fmaf(hv, w.y, acc2.y);
        acc2.z = fmaf(hv, w.z, acc2.z);
        acc2.w = fmaf(hv, w.w, acc2.w);
    }
    float4 o;
    o.x = fmaxf(acc2.x, 0.f) * msk;
    o.y = fmaxf(acc2.y, 0.f) * msk;
    o.z = fmaxf(acc2.z, 0.f) * msk;
    o.w = fmaxf(acc2.w, 0.f) * msk;
    ((float4*)out)[(size_t)(pbase + pos) * 16 + g] = o;   // lane-contiguous
}

// ---------------------------------------------------------------------------
extern "C" void kernel_launch(void* const* d_in, const int* in_sizes, int n_in,
                              void* d_out, int out_size, void* d_ws, size_t ws_size,
                              hipStream_t stream)
{
    const float* times  = (const float*)d_in[0];
    const float* vals   = (const float*)d_in[1];
    const int*   meas   = (const int*)d_in[2];
    const float* mask   = (const float*)d_in[3];
    const float* psi_w1 = (const float*)d_in[4];
    const float* psi_b1 = (const float*)d_in[5];
    const float* psi_w2 = (const float*)d_in[6];
    const float* psi_b2 = (const float*)d_in[7];
    const float* arho_w = (const float*)d_in[8];
    const float* arho_b = (const float*)d_in[9];
    const float* W_k    = (const float*)d_in[10];
    const float* W_q    = (const float*)d_in[11];
    const float* phi_w1 = (const float*)d_in[12];
    const float* phi_b1 = (const float*)d_in[13];
    const float* phi_w2 = (const float*)d_in[14];
    const float* phi_b2 = (const float*)d_in[15];
    const float* rho_w1 = (const float*)d_in[16];
    const float* rho_b1 = (const float*)d_in[17];
    const float* rho_w2 = (const float*)d_in[18];
    const float* rho_b2 = (const float*)d_in[19];
    float* ws  = (float*)d_ws;
    float* out = (float*)d_out;

    k_encode<<<dim3(128), dim3(64), 0, stream>>>(times, vals, meas, mask,
        psi_w1, psi_b1, psi_w2, psi_b2, phi_w1, phi_b1, phi_w2, phi_b2,
        arho_w, arho_b, W_k, W_q, ws);
    k_mid<<<dim3(528), dim3(64), 0, stream>>>(ws);
    k_rho<<<dim3(512), dim3(256), 0, stream>>>(rho_w1, rho_b1, rho_w2, rho_b2, ws, out);
}

// Round 5
// 135.488 us; speedup vs baseline: 1.5262x; 1.0325x over previous
//
#include <hip/hip_runtime.h>
#include <math.h>

// Problem constants
#define PB 2048          // P (sequence length)
// ws layout (float offsets), all [b][chan][p] transposed for coalescing
#define OFF_ENC 0        // enc_t (phi output): [4][32][2048]
#define OFF_Q   262144   // q = psi@V : [4][4][2048]
#define OFF_R   294912   // r = comb@U + c : [4][4][2048]
#define OFF_MSK 327680   // mask: [4][2048]
#define OFF_WV  335872   // wv: [16][33][2048] (scan of w, w*enc)

// ---------------------------------------------------------------------------
// K1: per-position encode, 2 lanes per position (halves exchanged via
// __shfl_xor(.,32) -- both halves live in the same wave64).
//   combined(31) -> phi MLP -> enc_t
//   combined(31) -> psi MLP -> q = psi2 @ V   (V = arho_w @ U2, folded here)
//   r = comb @ U[0:31] + arho_b @ U2          (U = fold(W_k,W_q)/sqrt(DOT))
// Linearity: cumsum(psi)@V == cumsum(psi@V), so only 4 scan channels remain.
__global__ __launch_bounds__(64) void k_encode(
    const float* __restrict__ times, const float* __restrict__ vals,
    const int* __restrict__ meas, const float* __restrict__ mask,
    const float* __restrict__ psi_w1, const float* __restrict__ psi_b1,
    const float* __restrict__ psi_w2, const float* __restrict__ psi_b2,
    const float* __restrict__ phi_w1, const float* __restrict__ phi_b1,
    const float* __restrict__ phi_w2, const float* __restrict__ phi_b2,
    const float* __restrict__ arho_w, const float* __restrict__ arho_b,
    const float* __restrict__ W_k, const float* __restrict__ W_q,
    float* __restrict__ ws)
{
    // psi_w1 31x33 [0,1023), psi_b1 [1023,1055), psi_w2 [1055,2079), psi_b2 [2079,2111)
    // phi_w1 31x33 [2111,3134), phi_b1 [3134,3166), phi_w2 [3166,4190), phi_b2 [4190,4222)
    __shared__ float sW[4222];
    __shared__ float sU[31*4];    // combined-part columns of folded key matrix
    __shared__ float sU2[32*4];   // agg-part columns (temp)
    __shared__ float sV[32*4];    // arho_w @ U2
    __shared__ float sCc[4];      // arho_b @ U2
    for (int i = threadIdx.x; i < 1023; i += 64) {
        int r = i / 33, cc = i - r * 33;
        sW[i]        = (cc < 32) ? psi_w1[r*32 + cc] : 0.0f;
        sW[2111 + i] = (cc < 32) ? phi_w1[r*32 + cc] : 0.0f;
    }
    for (int i = threadIdx.x; i < 1024; i += 64) {
        sW[1055 + i] = psi_w2[i];
        sW[3166 + i] = phi_w2[i];
    }
    if (threadIdx.x < 32) {
        int i = threadIdx.x;
        sW[1023 + i] = psi_b1[i];
        sW[2079 + i] = psi_b2[i];
        sW[3134 + i] = phi_b1[i];
        sW[4190 + i] = phi_b2[i];
    }
    for (int t = threadIdx.x; t < 252; t += 64) {
        int i = t >> 2, h = t & 3;
        float s = 0.0f;
        #pragma unroll
        for (int d = 0; d < 16; d++)
            s = fmaf(W_k[i*64 + d*4 + h], W_q[h*16 + d], s);
        s *= 0.25f;   // 1/sqrt(16)
        if (i < 31) sU[i*4 + h] = s; else sU2[(i-31)*4 + h] = s;
    }
    __syncthreads();
    for (int t = threadIdx.x; t < 128; t += 64) {
        int ch = t >> 2, h = t & 3;
        float s = 0.0f;
        #pragma unroll
        for (int j = 0; j < 32; j++)
            s = fmaf(arho_w[ch*32 + j], sU2[j*4 + h], s);
        sV[t] = s;
    }
    if (threadIdx.x < 4) {
        float s = 0.0f;
        #pragma unroll
        for (int j = 0; j < 32; j++)
            s = fmaf(arho_b[j], sU2[j*4 + threadIdx.x], s);
        sCc[threadIdx.x] = s;
    }
    __syncthreads();

    const int tid  = threadIdx.x;
    const int half = tid >> 5;              // 0: j in [0,16), 1: j in [16,32)
    const int jb   = half << 4;             // own output base
    const int pp = blockIdx.x * 32 + (tid & 31);
    const int b = pp >> 11, p = pp & 2047;
    const float t = times[pp];
    const float v = vals[pp];
    const float msk = mask[pp];
    const int m = meas[pp];

    float c[9];
    c[0] = sinf(t);           c[1] = cosf(t);
    c[2] = sinf(t * 0.1f);    c[3] = cosf(t * 0.1f);
    c[4] = sinf(t * 0.01f);   c[5] = cosf(t * 0.01f);
    c[6] = sinf(t * 0.001f);  c[7] = cosf(t * 0.001f);
    c[8] = v;

    float* enc_t = ws + OFF_ENC;
    const int cb = b * 32;

    float x[9];
    #pragma unroll
    for (int i = 0; i < 9; i++) x[i] = c[i] * msk;
    const float ohs = (m > 0) ? msk : 0.0f;
    const int   ohr = (m > 0) ? (8 + m) * 33 : 0;

    // ---- r = comb @ U + arho_b@U2 (combined raw/unmasked, per reference) --
    if (half == 0) {
        float r[4] = {sCc[0], sCc[1], sCc[2], sCc[3]};
        #pragma unroll
        for (int i = 0; i < 9; i++) {
            #pragma unroll
            for (int h = 0; h < 4; h++) r[h] = fmaf(c[i], sU[i*4 + h], r[h]);
        }
        if (m > 0) {
            #pragma unroll
            for (int h = 0; h < 4; h++) r[h] += sU[(8 + m)*4 + h];
        }
        #pragma unroll
        for (int h = 0; h < 4; h++)
            ws[OFF_R + (size_t)(b*4 + h) * PB + p] = r[h];
        ws[OFF_MSK + (size_t)b * PB + p] = msk;
    }

    // ---- psi MLP -> q ----
    {
        float h1o[16];
        #pragma unroll
        for (int jj = 0; jj < 16; jj++) {
            const int j = jb + jj;
            float acc = sW[1023 + j];
            #pragma unroll
            for (int i = 0; i < 9; i++) acc = fmaf(x[i], sW[i*33 + j], acc);
            acc = fmaf(ohs, sW[ohr + j], acc);
            h1o[jj] = fmaxf(acc, 0.0f) * msk;
        }
        float h1f[32];
        #pragma unroll
        for (int jj = 0; jj < 16; jj++) {
            const float other = __shfl_xor(h1o[jj], 32);
            h1f[jj]      = half ? other   : h1o[jj];
            h1f[16 + jj] = half ? h1o[jj] : other;
        }
        float q[4] = {0.f, 0.f, 0.f, 0.f};
        #pragma unroll
        for (int jj = 0; jj < 16; jj++) {
            const int j = jb + jj;
            float acc = sW[2079 + j];
            #pragma unroll
            for (int i = 0; i < 32; i++) acc = fmaf(h1f[i], sW[1055 + i*32 + j], acc);
            const float p2 = fmaxf(acc, 0.0f) * msk;
            #pragma unroll
            for (int h = 0; h < 4; h++) q[h] = fmaf(p2, sV[j*4 + h], q[h]);
        }
        #pragma unroll
        for (int h = 0; h < 4; h++) q[h] += __shfl_xor(q[h], 32);
        if (half == 0) {
            #pragma unroll
            for (int h = 0; h < 4; h++)
                ws[OFF_Q + (size_t)(b*4 + h) * PB + p] = q[h];
        }
    }
    // ---- phi MLP -> enc_t ----
    {
        float h1o[16];
        #pragma unroll
        for (int jj = 0; jj < 16; jj++) {
            const int j = jb + jj;
            float acc = sW[3134 + j];
            #pragma unroll
            for (int i = 0; i < 9; i++) acc = fmaf(x[i], sW[2111 + i*33 + j], acc);
            acc = fmaf(ohs, sW[2111 + ohr + j], acc);
            h1o[jj] = fmaxf(acc, 0.0f) * msk;
        }
        float h1f[32];
        #pragma unroll
        for (int jj = 0; jj < 16; jj++) {
            const float other = __shfl_xor(h1o[jj], 32);
            h1f[jj]      = half ? other   : h1o[jj];
            h1f[16 + jj] = half ? h1o[jj] : other;
        }
        #pragma unroll
        for (int jj = 0; jj < 16; jj++) {
            const int j = jb + jj;
            float acc = sW[4190 + j];
            #pragma unroll
            for (int i = 0; i < 32; i++) acc = fmaf(h1f[i], sW[3166 + i*32 + j], acc);
            enc_t[(size_t)(cb + j) * PB + p] = fmaxf(acc, 0.0f) * msk;
        }
    }
}

// ---------------------------------------------------------------------------
// K2: fused scan+exp+weight-mul+scan. Block = one (bh, c), c in [0,33):
//   cumq = inclusive-scan(q[bh])                       (redundant per c: cheap)
//   ex   = exp(msk * (r[bh] + cumq/(p+1)))
//   v    = (c==0) ? ex : ex * enc[b][c-1]
//   wv[bh][c] = inclusive-scan(v)
__global__ __launch_bounds__(64) void k_mid(float* __restrict__ ws)
{
    const int blk = blockIdx.x;
    const int bh = blk / 33;
    const int c  = blk - bh * 33;
    const int b  = bh >> 2;
    const int lane = threadIdx.x;

    const float4* q4 = (const float4*)(ws + OFF_Q   + (size_t)bh * PB + lane * 32);
    const float4* r4 = (const float4*)(ws + OFF_R   + (size_t)bh * PB + lane * 32);
    const float4* m4 = (const float4*)(ws + OFF_MSK + (size_t)b  * PB + lane * 32);
    const float4* e4 = (const float4*)(ws + OFF_ENC + ((size_t)(b*32 + (c-1))) * PB + lane * 32);
    float4* o4 = (float4*)(ws + OFF_WV + ((size_t)(bh*33 + c)) * PB + lane * 32);

    float vq[32];
    #pragma unroll
    for (int k = 0; k < 8; k++) {
        float4 f = q4[k];
        vq[4*k] = f.x; vq[4*k+1] = f.y; vq[4*k+2] = f.z; vq[4*k+3] = f.w;
    }
    // inclusive scan of q
    #pragma unroll
    for (int j = 1; j < 32; j++) vq[j] += vq[j-1];
    {
        const float tot = vq[31];
        float x = tot;
        #pragma unroll
        for (int off = 1; off < 64; off <<= 1) {
            float y = __shfl_up(x, off);
            if (lane >= off) x += y;
        }
        const float excl = x - tot;
        #pragma unroll
        for (int j = 0; j < 32; j++) vq[j] += excl;
    }
    // ex = exp(msk*(r + cumq/(p+1))), then multiply by enc channel
    float v[32];
    #pragma unroll
    for (int k = 0; k < 8; k++) {
        const float4 fr = r4[k];
        const float4 fm = m4[k];
        const int p0 = lane * 32 + 4*k;
        v[4*k+0] = expf(fm.x * (fr.x + vq[4*k+0] / (float)(p0 + 1)));
        v[4*k+1] = expf(fm.y * (fr.y + vq[4*k+1] / (float)(p0 + 2)));
        v[4*k+2] = expf(fm.z * (fr.z + vq[4*k+2] / (float)(p0 + 3)));
        v[4*k+3] = expf(fm.w * (fr.w + vq[4*k+3] / (float)(p0 + 4)));
    }
    if (c > 0) {
        #pragma unroll
        for (int k = 0; k < 8; k++) {
            float4 f = e4[k];
            v[4*k] *= f.x; v[4*k+1] *= f.y; v[4*k+2] *= f.z; v[4*k+3] *= f.w;
        }
    }
    // inclusive scan of v
    #pragma unroll
    for (int j = 1; j < 32; j++) v[j] += v[j-1];
    const float tot = v[31];
    float x = tot;
    #pragma unroll
    for (int off = 1; off < 64; off <<= 1) {
        float y = __shfl_up(x, off);
        if (lane >= off) x += y;
    }
    const float excl = x - tot;
    #pragma unroll
    for (int j = 0; j < 32; j++) v[j] += excl;
    #pragma unroll
    for (int k = 0; k < 8; k++)
        o4[k] = make_float4(v[4*k], v[4*k+1], v[4*k+2], v[4*k+3]);
}

// ---------------------------------------------------------------------------
// K3: out5 = C/L -> agg2(128) -> rho MLP (128->64->64).
// 512 blocks x 256 threads; block = 16 positions; thread = (pos, 4-output
// group). Weights via coalesced float4 global loads (L1-hot, 48 KB total).
__global__ __launch_bounds__(256) void k_rho(
    const float* __restrict__ rho_w1, const float* __restrict__ rho_b1,
    const float* __restrict__ rho_w2, const float* __restrict__ rho_b2,
    const float* __restrict__ ws, float* __restrict__ out)
{
    __shared__ float h1s[16][65];   // [pos][j], 65 keeps banks spread
    __shared__ float scl[16][4];    // msk/L per (pos,h)
    __shared__ float mskS[16];
    const int tid = threadIdx.x;
    const int pos = tid >> 4;       // 0..15
    const int g   = tid & 15;       // output group of 4
    const int pbase = blockIdx.x * 16;
    const int b  = pbase >> 11;
    const int p0 = pbase & 2047;
    const float* wv = ws + OFF_WV + (size_t)b * 132 * PB;   // 4*33 channels

    if (tid < 64) {
        const int pp = tid >> 2, h = tid & 3;
        const float msk = ws[OFF_MSK + (size_t)b * PB + p0 + pp];
        const float L = wv[(size_t)(h*33) * PB + p0 + pp];
        scl[pp][h] = msk / L;
        if (h == 0) mskS[pp] = msk;
    }
    __syncthreads();

    const int pg = p0 + pos;
    float4 acc = ((const float4*)rho_b1)[g];
    const float4* w14 = (const float4*)rho_w1;
    const float sc0 = scl[pos][0], sc1 = scl[pos][1];
    const float sc2 = scl[pos][2], sc3 = scl[pos][3];
    #pragma unroll
    for (int h = 0; h < 4; h++) {
        const float sc = (h == 0) ? sc0 : (h == 1) ? sc1 : (h == 2) ? sc2 : sc3;
        const float* wvh = wv + (size_t)(h*33 + 1) * PB + pg;
        #pragma unroll 8
        for (int d = 0; d < 32; d++) {
            const float ai = wvh[(size_t)d * PB] * sc;
            const float4 w = w14[(h*32 + d)*16 + g];
            acc.x = fmaf(ai, w.x, acc.x);
            acc.y = fmaf(ai, w.y, acc.y);
            acc.z = fmaf(ai, w.z, acc.z);
            acc.w = fmaf(ai, w.w, acc.w);
        }
    }
    const float msk = mskS[pos];
    h1s[pos][g*4+0] = fmaxf(acc.x, 0.f) * msk;
    h1s[pos][g*4+1] = fmaxf(acc.y, 0.f) * msk;
    h1s[pos][g*4+2] = fmaxf(acc.z, 0.f) * msk;
    h1s[pos][g*4+3] = fmaxf(acc.w, 0.f) * msk;
    __syncthreads();

    float4 acc2 = ((const float4*)rho_b2)[g];
    const float4* w24 = (const float4*)rho_w2;
    #pragma unroll 16
    for (int i = 0; i < 64; i++) {
        const float hv = h1s[pos][i];
        const float4 w = w24[i*16 + g];
        acc2.x = fmaf(hv, w.x, acc2.x);
        acc2.y = fmaf(hv, w.y, acc2.y);
        acc2.z = fmaf(hv, w.z, acc2.z);
        acc2.w = fmaf(hv, w.w, acc2.w);
    }
    float4 o;
    o.x = fmaxf(acc2.x, 0.f) * msk;
    o.y = fmaxf(acc2.y, 0.f) * msk;
    o.z = fmaxf(acc2.z, 0.f) * msk;
    o.w = fmaxf(acc2.w, 0.f) * msk;
    ((float4*)out)[(size_t)(pbase + pos) * 16 + g] = o;   // lane-contiguous
}

// ---------------------------------------------------------------------------
extern "C" void kernel_launch(void* const* d_in, const int* in_sizes, int n_in,
                              void* d_out, int out_size, void* d_ws, size_t ws_size,
                              hipStream_t stream)
{
    const float* times  = (const float*)d_in[0];
    const float* vals   = (const float*)d_in[1];
    const int*   meas   = (const int*)d_in[2];
    const float* mask   = (const float*)d_in[3];
    const float* psi_w1 = (const float*)d_in[4];
    const float* psi_b1 = (const float*)d_in[5];
    const float* psi_w2 = (const float*)d_in[6];
    const float* psi_b2 = (const float*)d_in[7];
    const float* arho_w = (const float*)d_in[8];
    const float* arho_b = (const float*)d_in[9];
    const float* W_k    = (const float*)d_in[10];
    const float* W_q    = (const float*)d_in[11];
    const float* phi_w1 = (const float*)d_in[12];
    const float* phi_b1 = (const float*)d_in[13];
    const float* phi_w2 = (const float*)d_in[14];
    const float* phi_b2 = (const float*)d_in[15];
    const float* rho_w1 = (const float*)d_in[16];
    const float* rho_b1 = (const float*)d_in[17];
    const float* rho_w2 = (const float*)d_in[18];
    const float* rho_b2 = (const float*)d_in[19];
    float* ws  = (float*)d_ws;
    float* out = (float*)d_out;

    k_encode<<<dim3(256), dim3(64), 0, stream>>>(times, vals, meas, mask,
        psi_w1, psi_b1, psi_w2, psi_b2, phi_w1, phi_b1, phi_w2, phi_b2,
        arho_w, arho_b, W_k, W_q, ws);
    k_mid<<<dim3(528), dim3(64), 0, stream>>>(ws);
    k_rho<<<dim3(512), dim3(256), 0, stream>>>(rho_w1, rho_b1, rho_w2, rho_b2, ws, out);
}